// Round 1
// 423.821 us; speedup vs baseline: 1.0272x; 1.0272x over previous
//
#include <hip/hip_runtime.h>

#define T_ 8
#define N_ 50000
#define E_ 800000
#define C_ 64

typedef __attribute__((ext_vector_type(8))) short bf16x8;
typedef __attribute__((ext_vector_type(4))) float f32x4;

__device__ inline short f2bf(float f) {
    union { float f; unsigned int u; } v; v.f = f;
    unsigned int u = v.u + 0x7FFFu + ((v.u >> 16) & 1u);  // RNE
    return (short)(u >> 16);
}
__device__ inline float bf2f_lo(unsigned int u) {
    union { unsigned int u; float f; } v; v.u = u << 16;
    return v.f;
}
__device__ inline float bf2f_hi(unsigned int u) {
    union { unsigned int u; float f; } v; v.u = u & 0xffff0000u;
    return v.f;
}

#define SCAN_TILES 49  // ceil(N / 1024)

// ---------------------------------------------------------------------------
// 1) fused: hist (blocks [0,3125)) + xcvt (blocks [3125,15625)) + wprep (rest)
//    xcvt now writes NODE-MAJOR xb: xb[n][t][c] (1024 B per node, so each
//    edge gather is one contiguous 1 KB block instead of 8 scattered 128 B).
__global__ __launch_bounds__(256) void fused_prep_kernel(
        const int* __restrict__ src, const int* __restrict__ dst,
        const float* __restrict__ w,
        float* __restrict__ degw, int* __restrict__ cnt,
        const float* __restrict__ x, unsigned short* __restrict__ xb,
        const float* __restrict__ Wz0, const float* __restrict__ Wz1,
        const float* __restrict__ Wh0, const float* __restrict__ Wh1,
        short* __restrict__ swz) {
    if (blockIdx.x < 3125) {
        int e = blockIdx.x * 256 + threadIdx.x;
        if (e < E_) {
            atomicAdd(&degw[src[e]], w[e]);
            atomicAdd(&cnt[dst[e]], 1);
        }
    } else if (blockIdx.x < 15625) {
        // id -> (n, t, c8): write addr (shorts) = n*512 + t*64 + c8*8 = id*8
        int id = (blockIdx.x - 3125) * 256 + threadIdx.x;
        int c8 = id & 7;
        int t = (id >> 3) & 7;
        int n = id >> 6;
        const float* xr = x + ((long long)t * N_ + n) * C_ + c8 * 8;
        float4 a = *(const float4*)(xr);
        float4 b = *(const float4*)(xr + 4);
        bf16x8 o;
        o[0] = f2bf(a.x); o[1] = f2bf(a.y); o[2] = f2bf(a.z); o[3] = f2bf(a.w);
        o[4] = f2bf(b.x); o[5] = f2bf(b.y); o[6] = f2bf(b.z); o[7] = f2bf(b.w);
        *(bf16x8*)(xb + (long long)id * 8) = o;
    } else {
        int idx = (blockIdx.x - 15625) * 256 + threadIdx.x;  // < 16384
        int j = idx & 7;
        int lane = (idx >> 3) & 63;
        int kb = (idx >> 9) & 1;
        int c = (idx >> 10) & 3;
        int mat = idx >> 12;
        const float* W = (mat == 0) ? Wz0 : (mat == 1) ? Wz1 : (mat == 2) ? Wh0 : Wh1;
        int k = kb * 32 + (lane >> 4) * 8 + j;
        int n = c * 16 + (lane & 15);
        swz[idx] = f2bf(W[k * 64 + n]);
    }
}

// 2a) parallel scan pass A: per-tile exclusive scan + tile totals
__global__ __launch_bounds__(1024) void scan_a_kernel(const int* __restrict__ cnt,
                                                      int* __restrict__ rowptr,
                                                      int* __restrict__ tsum) {
    __shared__ int wsum[16];
    int tid = threadIdx.x, lane = tid & 63, wid = tid >> 6;
    int idx = blockIdx.x * 1024 + tid;
    int orig = (idx < N_) ? cnt[idx] : 0;
    int v = orig;
#pragma unroll
    for (int off = 1; off < 64; off <<= 1) {
        int u = __shfl_up(v, off);
        if (lane >= off) v += u;
    }
    if (lane == 63) wsum[wid] = v;
    __syncthreads();
    if (wid == 0) {
        int s = (lane < 16) ? wsum[lane] : 0;
#pragma unroll
        for (int off = 1; off < 16; off <<= 1) {
            int u = __shfl_up(s, off);
            if (lane >= off) s += u;
        }
        if (lane < 16) wsum[lane] = s;
    }
    __syncthreads();
    int wpre = wid ? wsum[wid - 1] : 0;
    if (idx < N_) rowptr[idx] = wpre + v - orig;
    if (tid == 0) tsum[blockIdx.x] = wsum[15];
}

// 2b) pass B: every block redundantly scans the 49 tile totals, adds its offset
__global__ __launch_bounds__(1024) void scan_b_kernel(const int* __restrict__ tsum,
                                                      int* __restrict__ rowptr) {
    __shared__ int soff[SCAN_TILES];
    __shared__ int stot;
    int tid = threadIdx.x, lane = tid & 63, wid = tid >> 6;
    if (wid == 0) {
        int own = (lane < SCAN_TILES) ? tsum[lane] : 0;
        int s = own;
#pragma unroll
        for (int off = 1; off < 64; off <<= 1) {
            int u = __shfl_up(s, off);
            if (lane >= off) s += u;
        }
        if (lane < SCAN_TILES) soff[lane] = s - own;  // exclusive
        if (lane == SCAN_TILES - 1) stot = s;
    }
    __syncthreads();
    int off = soff[blockIdx.x];
    int idx = blockIdx.x * 1024 + tid;
    if (idx < N_) rowptr[idx] += off;
    if (blockIdx.x == SCAN_TILES - 1 && tid == 0) rowptr[N_] = stot;
}

// 3) reorder edges into CSR-by-dst, dinv fused. Afterwards rowptr[d]==end(d),
//    start(d)==(d?rowptr[d-1]:0). Packs {src,nw}.
__global__ void reorder_kernel(const int* __restrict__ src, const int* __restrict__ dst,
                               const float* __restrict__ w, const float* __restrict__ degw,
                               int* __restrict__ rowptr, int2* __restrict__ es, int E) {
    int e = blockIdx.x * blockDim.x + threadIdx.x;
    if (e < E) {
        int s = src[e], d = dst[e];
        float ds = degw[s], dd = degw[d];
        float is = ds > 0.f ? rsqrtf(fmaxf(ds, 1e-12f)) : 0.f;
        float id = dd > 0.f ? rsqrtf(fmaxf(dd, 1e-12f)) : 0.f;
        float nwv = -w[e] * is * id;
        int pos = atomicAdd(&rowptr[d], 1);
        es[pos] = make_int2(s, __float_as_int(nwv));
    }
}

// accumulate one weighted bf16x8 row-slice into acc[8]
#define ACC8(W, V)                                                       \
    acc[0] += (W) * bf2f_lo((V).x); acc[1] += (W) * bf2f_hi((V).x);      \
    acc[2] += (W) * bf2f_lo((V).y); acc[3] += (W) * bf2f_hi((V).y);      \
    acc[4] += (W) * bf2f_lo((V).z); acc[5] += (W) * bf2f_hi((V).z);      \
    acc[6] += (W) * bf2f_lo((V).w); acc[7] += (W) * bf2f_hi((V).w);

// 4) FUSED gather + node. Block = 4 nodes. Phase 1: each wave gathers one
//    node's tx1 rows (all 8 t) into a padded LDS tile — with node-major xb
//    each edge is ONE contiguous 1024 B wave-load (lane*16 B), 4 edges in
//    flight. Phase 2: waves switch to MFMA roles (wave = M-tile x {az,ah});
//    A-frags from xb/LDS, B-frags straight from L2-hot swz. Phase 3: az
//    crosses to the ah-wave via LDS (65-padded, conflict-free), epilogue +
//    Wlin reduce + scattered out writes.
__global__ __launch_bounds__(256) void gather_node_kernel(
        const int* __restrict__ rowptr, const int2* __restrict__ es,
        const unsigned short* __restrict__ xb, const short* __restrict__ swz,
        const float* __restrict__ bxz, const float* __restrict__ bhz,
        const float* __restrict__ bxh, const float* __restrict__ bhh,
        const float* __restrict__ Wlin, const float* __restrict__ blin,
        float* __restrict__ out) {
    __shared__ unsigned short ltx[32 * 72];  // 32 rows x 64 ch bf16, +8 pad
    __shared__ float laz[2][16][65];         // az exchange, +1 pad kills 4-way conflicts

    int lane = threadIdx.x & 63;
    int wid = threadIdx.x >> 6;
    int base = blockIdx.x * 4;

    // ---- phase 1: gather node d = base + wid (lane = t*8 + oct) ----
    {
        int d = base + wid;
        int t = lane >> 3;
        int oct = lane & 7;
        int start = d ? rowptr[d - 1] : 0;
        int end = rowptr[d];
        float acc[8] = {0.f, 0.f, 0.f, 0.f, 0.f, 0.f, 0.f, 0.f};
        // node-major: node record = 512 shorts; lane covers (t,oct) slice
        const unsigned short* xbase = xb + lane * 8;
        for (int b0 = start; b0 < end; b0 += 64) {
            int m = end - b0;
            if (m > 64) m = 64;
            int2 pk = (lane < m) ? es[b0 + lane] : make_int2(0, 0);
            int k = 0;
            for (; k + 3 < m; k += 4) {
                int s0 = __shfl(pk.x, k);
                int s1 = __shfl(pk.x, k + 1);
                int s2 = __shfl(pk.x, k + 2);
                int s3 = __shfl(pk.x, k + 3);
                uint4 v0 = *(const uint4*)(xbase + (long long)s0 * 512);
                uint4 v1 = *(const uint4*)(xbase + (long long)s1 * 512);
                uint4 v2 = *(const uint4*)(xbase + (long long)s2 * 512);
                uint4 v3 = *(const uint4*)(xbase + (long long)s3 * 512);
                float w0 = __int_as_float(__shfl(pk.y, k));
                float w1 = __int_as_float(__shfl(pk.y, k + 1));
                float w2 = __int_as_float(__shfl(pk.y, k + 2));
                float w3 = __int_as_float(__shfl(pk.y, k + 3));
                ACC8(w0, v0);
                ACC8(w1, v1);
                ACC8(w2, v2);
                ACC8(w3, v3);
            }
            for (; k < m; ++k) {
                int s0 = __shfl(pk.x, k);
                float w0 = __int_as_float(__shfl(pk.y, k));
                uint4 v0 = *(const uint4*)(xbase + (long long)s0 * 512);
                ACC8(w0, v0);
            }
        }
        uint4 o;
        o.x = (unsigned int)(unsigned short)f2bf(acc[0]) |
              ((unsigned int)(unsigned short)f2bf(acc[1]) << 16);
        o.y = (unsigned int)(unsigned short)f2bf(acc[2]) |
              ((unsigned int)(unsigned short)f2bf(acc[3]) << 16);
        o.z = (unsigned int)(unsigned short)f2bf(acc[4]) |
              ((unsigned int)(unsigned short)f2bf(acc[5]) << 16);
        o.w = (unsigned int)(unsigned short)f2bf(acc[6]) |
              ((unsigned int)(unsigned short)f2bf(acc[7]) << 16);
        int r = wid * 8 + t;  // block-row: r>>3 = node, r&7 = t
        *(uint4*)(ltx + r * 72 + oct * 8) = o;
    }
    __syncthreads();

    // ---- phase 2: MFMA. wave -> (M-tile mt, gate g: 0=az, 1=ah) ----
    int mt = wid >> 1;
    int g = wid & 1;
    int c16 = lane & 15;
    int kq = lane >> 4;
    int r_blk = mt * 16 + c16;
    // node-major row index = node*8 + t = base*8 + r_blk -> contiguous 2 KB/wave
    const unsigned short* xr = xb + (long long)(base * 8 + r_blk) * C_ + kq * 8;
    bf16x8 ax0 = *(const bf16x8*)(xr);
    bf16x8 ax1 = *(const bf16x8*)(xr + 32);
    bf16x8 at0 = *(const bf16x8*)(ltx + r_blk * 72 + kq * 8);
    bf16x8 at1 = *(const bf16x8*)(ltx + r_blk * 72 + 32 + kq * 8);

    const float* bA = g ? bxh : bxz;
    const float* bB = g ? bhh : bhz;
    const short* wA = swz + (2 * g) * 4096 + lane * 8;      // x-weight frags
    const short* wB = swz + (2 * g + 1) * 4096 + lane * 8;  // tx1-weight frags

    f32x4 a4[4];
#pragma unroll
    for (int c = 0; c < 4; ++c) {
        int col = c * 16 + c16;
        float bv = bA[col] + bB[col];
        a4[c] = (f32x4){bv, bv, bv, bv};
    }
#pragma unroll
    for (int c = 0; c < 4; ++c) {
        bf16x8 bA0 = *(const bf16x8*)(wA + (c * 2 + 0) * 512);
        bf16x8 bA1 = *(const bf16x8*)(wA + (c * 2 + 1) * 512);
        bf16x8 bB0 = *(const bf16x8*)(wB + (c * 2 + 0) * 512);
        bf16x8 bB1 = *(const bf16x8*)(wB + (c * 2 + 1) * 512);
        a4[c] = __builtin_amdgcn_mfma_f32_16x16x32_bf16(ax0, bA0, a4[c], 0, 0, 0);
        a4[c] = __builtin_amdgcn_mfma_f32_16x16x32_bf16(ax1, bA1, a4[c], 0, 0, 0);
        a4[c] = __builtin_amdgcn_mfma_f32_16x16x32_bf16(at0, bB0, a4[c], 0, 0, 0);
        a4[c] = __builtin_amdgcn_mfma_f32_16x16x32_bf16(at1, bB1, a4[c], 0, 0, 0);
    }

    // ---- phase 3: az -> LDS; ah-wave computes epilogue ----
    if (g == 0) {
#pragma unroll
        for (int c = 0; c < 4; ++c)
#pragma unroll
            for (int r = 0; r < 4; ++r)
                laz[mt][kq * 4 + r][c * 16 + c16] = a4[c][r];
    }
    __syncthreads();
    if (g == 1) {
        float part[4] = {0.f, 0.f, 0.f, 0.f};
#pragma unroll
        for (int c = 0; c < 4; ++c) {
            int col = c * 16 + c16;
            float wl = Wlin[col];
#pragma unroll
            for (int r = 0; r < 4; ++r) {
                float a = laz[mt][kq * 4 + r][col];
                float b = a4[c][r];
                float z = 1.f / (1.f + __expf(-a));
                float aa = fabsf(b);
                float e = __expf(-2.f * aa);
                float ht = copysignf((1.f - e) / (1.f + e), b);
                float h = fmaxf((1.f - z) * ht, 0.f);
                part[r] += h * wl;
            }
        }
#pragma unroll
        for (int m = 1; m <= 8; m <<= 1) {
#pragma unroll
            for (int r = 0; r < 4; ++r) part[r] += __shfl_xor(part[r], m);
        }
        if (c16 == 0) {
            float bl = blin[0];
#pragma unroll
            for (int r = 0; r < 4; ++r) {
                int rb = mt * 16 + kq * 4 + r;
                out[(long long)(rb & 7) * N_ + base + (rb >> 3)] = part[r] + bl;
            }
        }
    }
}

extern "C" void kernel_launch(void* const* d_in, const int* in_sizes, int n_in,
                              void* d_out, int out_size, void* d_ws, size_t ws_size,
                              hipStream_t stream) {
    const float* x    = (const float*)d_in[0];
    const int*   ei   = (const int*)d_in[1];
    const float* w    = (const float*)d_in[2];
    const float* Wxz0 = (const float*)d_in[3];
    const float* Wxz1 = (const float*)d_in[4];
    const float* bxz  = (const float*)d_in[5];
    const float* bhz  = (const float*)d_in[8];
    const float* Wxh0 = (const float*)d_in[15];
    const float* Wxh1 = (const float*)d_in[16];
    const float* bxh  = (const float*)d_in[17];
    const float* bhh  = (const float*)d_in[20];
    const float* Wlin = (const float*)d_in[21];
    const float* blin = (const float*)d_in[22];
    float* out = (float*)d_out;

    const int* src = ei;
    const int* dst = ei + E_;

    // workspace layout (512-aligned blocks):
    char* ws = (char*)d_ws;
    size_t off = 0;
    auto alloc = [&](size_t bytes) {
        char* p = ws + off;
        off = (off + bytes + 511) & ~(size_t)511;
        return p;
    };
    short* swz             = (short*)alloc(4 * 4096 * sizeof(short));           // 32 KB
    float* degw            = (float*)alloc((size_t)N_ * 4);
    int*   cnt             = (int*)alloc((size_t)N_ * 4);
    int*   rowptr          = (int*)alloc(((size_t)N_ + 1) * 4);
    int*   tsum            = (int*)alloc((size_t)SCAN_TILES * 4);
    int2*  es              = (int2*)alloc((size_t)E_ * 8);                      // 6.4 MB
    unsigned short* xb     = (unsigned short*)alloc((size_t)T_ * N_ * C_ * 2);  // 51.2 MB, node-major [n][t][c]

    hipMemsetAsync(degw, 0, (size_t)N_ * 4, stream);
    hipMemsetAsync(cnt, 0, (size_t)N_ * 4, stream);

    // hist (3125) + xcvt (12500) + wprep (64) = 15689 blocks
    fused_prep_kernel<<<15689, 256, 0, stream>>>(src, dst, w, degw, cnt,
                                                 x, xb, Wxz0, Wxz1, Wxh0, Wxh1, swz);
    scan_a_kernel<<<SCAN_TILES, 1024, 0, stream>>>(cnt, rowptr, tsum);
    scan_b_kernel<<<SCAN_TILES, 1024, 0, stream>>>(tsum, rowptr);
    reorder_kernel<<<(E_ + 255) / 256, 256, 0, stream>>>(src, dst, w, degw, rowptr, es, E_);

    // 12500 blocks x 4 nodes = 50000
    gather_node_kernel<<<N_ / 4, 256, 0, stream>>>(
        rowptr, es, xb, swz, bxz, bhz, bxh, bhh, Wlin, blin, out);
}

// Round 2
// 407.981 us; speedup vs baseline: 1.0671x; 1.0388x over previous
//
#include <hip/hip_runtime.h>

#define T_ 8
#define N_ 50000
#define E_ 800000
#define C_ 64
#define OVF_CAP 131072

typedef __attribute__((ext_vector_type(8))) short bf16x8;
typedef __attribute__((ext_vector_type(4))) float f32x4;

__device__ inline short f2bf(float f) {
    union { float f; unsigned int u; } v; v.f = f;
    unsigned int u = v.u + 0x7FFFu + ((v.u >> 16) & 1u);  // RNE
    return (short)(u >> 16);
}
__device__ inline float bf2f_lo(unsigned int u) {
    union { unsigned int u; float f; } v; v.u = u << 16;
    return v.f;
}
__device__ inline float bf2f_hi(unsigned int u) {
    union { unsigned int u; float f; } v; v.u = u & 0xffff0000u;
    return v.f;
}

// ---------------------------------------------------------------------------
// 1) fused: hist+bucket-scatter (blocks [0,3125)) + xcvt ([3125,15625)) +
//    wprep (rest). Replaces the old hist/scan/scan/reorder CSR build:
//    pos = atomicAdd(cnt[dst]) places {src, w} straight into a fixed-capacity
//    per-dst bucket. Overflow (deg > cap, impossible for this input but
//    handled for correctness) goes to a global list.
__global__ __launch_bounds__(256) void fused_prep_kernel(
        const int* __restrict__ src, const int* __restrict__ dst,
        const float* __restrict__ w,
        float* __restrict__ degw, int* __restrict__ cnt,
        int2* __restrict__ es, int cap,
        int* __restrict__ ovfcnt, int4* __restrict__ ovf,
        const float* __restrict__ x, unsigned short* __restrict__ xb,
        const float* __restrict__ Wz0, const float* __restrict__ Wz1,
        const float* __restrict__ Wh0, const float* __restrict__ Wh1,
        short* __restrict__ swz) {
    if (blockIdx.x < 3125) {
        int e = blockIdx.x * 256 + threadIdx.x;  // 3125*256 == E_ exactly
        int s = src[e], d = dst[e];
        float wv = w[e];
        atomicAdd(&degw[s], wv);
        int pos = atomicAdd(&cnt[d], 1);
        if (pos < cap) {
            es[d * cap + pos] = make_int2(s, __float_as_int(wv));
        } else {
            int op = atomicAdd(ovfcnt, 1);
            if (op < OVF_CAP) ovf[op] = make_int4(d, s, __float_as_int(wv), 0);
        }
    } else if (blockIdx.x < 15625) {
        // id -> (n, t, c8): write addr (shorts) = n*512 + t*64 + c8*8 = id*8
        int id = (blockIdx.x - 3125) * 256 + threadIdx.x;
        int c8 = id & 7;
        int t = (id >> 3) & 7;
        int n = id >> 6;
        const float* xr = x + ((long long)t * N_ + n) * C_ + c8 * 8;
        float4 a = *(const float4*)(xr);
        float4 b = *(const float4*)(xr + 4);
        bf16x8 o;
        o[0] = f2bf(a.x); o[1] = f2bf(a.y); o[2] = f2bf(a.z); o[3] = f2bf(a.w);
        o[4] = f2bf(b.x); o[5] = f2bf(b.y); o[6] = f2bf(b.z); o[7] = f2bf(b.w);
        *(bf16x8*)(xb + (long long)id * 8) = o;
    } else {
        int idx = (blockIdx.x - 15625) * 256 + threadIdx.x;  // < 16384
        int j = idx & 7;
        int lane = (idx >> 3) & 63;
        int kb = (idx >> 9) & 1;
        int c = (idx >> 10) & 3;
        int mat = idx >> 12;
        const float* W = (mat == 0) ? Wz0 : (mat == 1) ? Wz1 : (mat == 2) ? Wh0 : Wh1;
        int k = kb * 32 + (lane >> 4) * 8 + j;
        int n = c * 16 + (lane & 15);
        swz[idx] = f2bf(W[k * 64 + n]);
    }
}

// accumulate one weighted bf16x8 row-slice into acc[8]
#define ACC8(W, V)                                                       \
    acc[0] += (W) * bf2f_lo((V).x); acc[1] += (W) * bf2f_hi((V).x);      \
    acc[2] += (W) * bf2f_lo((V).y); acc[3] += (W) * bf2f_hi((V).y);      \
    acc[4] += (W) * bf2f_lo((V).z); acc[5] += (W) * bf2f_hi((V).z);      \
    acc[6] += (W) * bf2f_lo((V).w); acc[7] += (W) * bf2f_hi((V).w);

// 2) FUSED gather + node. Block = 4 nodes. Phase 1: each wave gathers one
//    node's tx1 rows (all 8 t) from its bucket — one aligned wave-load for
//    the bucket, nw computed on the fly from L2-resident degw, 8 edges in
//    flight. Phase 2: waves switch to MFMA roles (wave = M-tile x {az,ah}).
//    Phase 3: az crosses to the ah-wave via LDS, epilogue + Wlin reduce.
__global__ __launch_bounds__(256) void gather_node_kernel(
        const int* __restrict__ cnt, const int2* __restrict__ es, int cap,
        const float* __restrict__ degw,
        const int* __restrict__ ovfcnt, const int4* __restrict__ ovf,
        const unsigned short* __restrict__ xb, const short* __restrict__ swz,
        const float* __restrict__ bxz, const float* __restrict__ bhz,
        const float* __restrict__ bxh, const float* __restrict__ bhh,
        const float* __restrict__ Wlin, const float* __restrict__ blin,
        float* __restrict__ out) {
    __shared__ unsigned short ltx[32 * 72];  // 32 rows x 64 ch bf16, +8 pad
    __shared__ float laz[2][16][65];         // az exchange, +1 pad

    int lane = threadIdx.x & 63;
    int wid = threadIdx.x >> 6;
    int base = blockIdx.x * 4;

    // ---- phase 1: gather node d = base + wid (lane = t*8 + oct) ----
    {
        int d = base + wid;
        int t = lane >> 3;
        int oct = lane & 7;
        int m = cnt[d];
        int mb = m < cap ? m : cap;
        float dd = degw[d];
        float id = dd > 0.f ? rsqrtf(fmaxf(dd, 1e-12f)) : 0.f;

        // per-lane edge prep: one bucket load + one L2-hot degw gather
        int2 pk = (lane < mb) ? es[d * cap + lane] : make_int2(0, 0);
        float dsrc = degw[pk.x];
        float is = dsrc > 0.f ? rsqrtf(fmaxf(dsrc, 1e-12f)) : 0.f;
        float nw_l = -__int_as_float(pk.y) * is * id;

        float acc[8] = {0.f, 0.f, 0.f, 0.f, 0.f, 0.f, 0.f, 0.f};
        const unsigned short* xbase = xb + lane * 8;  // node record = 512 shorts
        int k = 0;
        for (; k + 7 < mb; k += 8) {
            int ss[8]; float ww[8];
#pragma unroll
            for (int j = 0; j < 8; ++j) {
                ss[j] = __shfl(pk.x, k + j);
                ww[j] = __shfl(nw_l, k + j);
            }
            uint4 vv[8];
#pragma unroll
            for (int j = 0; j < 8; ++j)
                vv[j] = *(const uint4*)(xbase + (long long)ss[j] * 512);
#pragma unroll
            for (int j = 0; j < 8; ++j) { ACC8(ww[j], vv[j]); }
        }
        for (; k < mb; ++k) {
            int s0 = __shfl(pk.x, k);
            float w0 = __shfl(nw_l, k);
            uint4 v0 = *(const uint4*)(xbase + (long long)s0 * 512);
            ACC8(w0, v0);
        }
        if (m > cap) {  // overflow path: never taken for this input
            int oc = *ovfcnt;
            if (oc > OVF_CAP) oc = OVF_CAP;
            for (int i = 0; i < oc; ++i) {
                int4 o = ovf[i];  // uniform addr -> broadcast
                if (o.x == d) {
                    float ds = degw[o.y];
                    float is2 = ds > 0.f ? rsqrtf(fmaxf(ds, 1e-12f)) : 0.f;
                    float w0 = -__int_as_float(o.z) * is2 * id;
                    uint4 v0 = *(const uint4*)(xbase + (long long)o.y * 512);
                    ACC8(w0, v0);
                }
            }
        }
        uint4 ob;
        ob.x = (unsigned int)(unsigned short)f2bf(acc[0]) |
               ((unsigned int)(unsigned short)f2bf(acc[1]) << 16);
        ob.y = (unsigned int)(unsigned short)f2bf(acc[2]) |
               ((unsigned int)(unsigned short)f2bf(acc[3]) << 16);
        ob.z = (unsigned int)(unsigned short)f2bf(acc[4]) |
               ((unsigned int)(unsigned short)f2bf(acc[5]) << 16);
        ob.w = (unsigned int)(unsigned short)f2bf(acc[6]) |
               ((unsigned int)(unsigned short)f2bf(acc[7]) << 16);
        int r = wid * 8 + t;  // block-row: r>>3 = node, r&7 = t
        *(uint4*)(ltx + r * 72 + oct * 8) = ob;
    }
    __syncthreads();

    // ---- phase 2: MFMA. wave -> (M-tile mt, gate g: 0=az, 1=ah) ----
    int mt = wid >> 1;
    int g = wid & 1;
    int c16 = lane & 15;
    int kq = lane >> 4;
    int r_blk = mt * 16 + c16;
    // node-major row index = node*8 + t = base*8 + r_blk -> contiguous 2 KB/wave
    const unsigned short* xr = xb + (long long)(base * 8 + r_blk) * C_ + kq * 8;
    bf16x8 ax0 = *(const bf16x8*)(xr);
    bf16x8 ax1 = *(const bf16x8*)(xr + 32);
    bf16x8 at0 = *(const bf16x8*)(ltx + r_blk * 72 + kq * 8);
    bf16x8 at1 = *(const bf16x8*)(ltx + r_blk * 72 + 32 + kq * 8);

    const float* bA = g ? bxh : bxz;
    const float* bB = g ? bhh : bhz;
    const short* wA = swz + (2 * g) * 4096 + lane * 8;      // x-weight frags
    const short* wB = swz + (2 * g + 1) * 4096 + lane * 8;  // tx1-weight frags

    f32x4 a4[4];
#pragma unroll
    for (int c = 0; c < 4; ++c) {
        int col = c * 16 + c16;
        float bv = bA[col] + bB[col];
        a4[c] = (f32x4){bv, bv, bv, bv};
    }
#pragma unroll
    for (int c = 0; c < 4; ++c) {
        bf16x8 bA0 = *(const bf16x8*)(wA + (c * 2 + 0) * 512);
        bf16x8 bA1 = *(const bf16x8*)(wA + (c * 2 + 1) * 512);
        bf16x8 bB0 = *(const bf16x8*)(wB + (c * 2 + 0) * 512);
        bf16x8 bB1 = *(const bf16x8*)(wB + (c * 2 + 1) * 512);
        a4[c] = __builtin_amdgcn_mfma_f32_16x16x32_bf16(ax0, bA0, a4[c], 0, 0, 0);
        a4[c] = __builtin_amdgcn_mfma_f32_16x16x32_bf16(ax1, bA1, a4[c], 0, 0, 0);
        a4[c] = __builtin_amdgcn_mfma_f32_16x16x32_bf16(at0, bB0, a4[c], 0, 0, 0);
        a4[c] = __builtin_amdgcn_mfma_f32_16x16x32_bf16(at1, bB1, a4[c], 0, 0, 0);
    }

    // ---- phase 3: az -> LDS; ah-wave computes epilogue ----
    if (g == 0) {
#pragma unroll
        for (int c = 0; c < 4; ++c)
#pragma unroll
            for (int r = 0; r < 4; ++r)
                laz[mt][kq * 4 + r][c * 16 + c16] = a4[c][r];
    }
    __syncthreads();
    if (g == 1) {
        float part[4] = {0.f, 0.f, 0.f, 0.f};
#pragma unroll
        for (int c = 0; c < 4; ++c) {
            int col = c * 16 + c16;
            float wl = Wlin[col];
#pragma unroll
            for (int r = 0; r < 4; ++r) {
                float a = laz[mt][kq * 4 + r][col];
                float b = a4[c][r];
                float z = 1.f / (1.f + __expf(-a));
                float aa = fabsf(b);
                float e = __expf(-2.f * aa);
                float ht = copysignf((1.f - e) / (1.f + e), b);
                float h = fmaxf((1.f - z) * ht, 0.f);
                part[r] += h * wl;
            }
        }
#pragma unroll
        for (int m = 1; m <= 8; m <<= 1) {
#pragma unroll
            for (int r = 0; r < 4; ++r) part[r] += __shfl_xor(part[r], m);
        }
        if (c16 == 0) {
            float bl = blin[0];
#pragma unroll
            for (int r = 0; r < 4; ++r) {
                int rb = mt * 16 + kq * 4 + r;
                out[(long long)(rb & 7) * N_ + base + (rb >> 3)] = part[r] + bl;
            }
        }
    }
}

extern "C" void kernel_launch(void* const* d_in, const int* in_sizes, int n_in,
                              void* d_out, int out_size, void* d_ws, size_t ws_size,
                              hipStream_t stream) {
    const float* x    = (const float*)d_in[0];
    const int*   ei   = (const int*)d_in[1];
    const float* w    = (const float*)d_in[2];
    const float* Wxz0 = (const float*)d_in[3];
    const float* Wxz1 = (const float*)d_in[4];
    const float* bxz  = (const float*)d_in[5];
    const float* bhz  = (const float*)d_in[8];
    const float* Wxh0 = (const float*)d_in[15];
    const float* Wxh1 = (const float*)d_in[16];
    const float* bxh  = (const float*)d_in[17];
    const float* bhh  = (const float*)d_in[20];
    const float* Wlin = (const float*)d_in[21];
    const float* blin = (const float*)d_in[22];
    float* out = (float*)d_out;

    const int* src = ei;
    const int* dst = ei + E_;

    // workspace layout (512-aligned blocks):
    char* ws = (char*)d_ws;
    size_t off = 0;
    auto alloc = [&](size_t bytes) {
        char* p = ws + off;
        off = (off + bytes + 511) & ~(size_t)511;
        return p;
    };
    short* swz         = (short*)alloc(4 * 4096 * sizeof(short));           // 32 KB
    float* degw        = (float*)alloc((size_t)N_ * 4);
    int*   cnt         = (int*)alloc((size_t)N_ * 4);
    int*   ovfcnt      = (int*)alloc(512);
    int4*  ovf         = (int4*)alloc((size_t)OVF_CAP * 16);                // 2 MB
    unsigned short* xb = (unsigned short*)alloc((size_t)T_ * N_ * C_ * 2);  // 51.2 MB
    size_t fixed = off;

    // pick the largest bucket capacity that fits the workspace
    int cap = 16;
    for (int c : {64, 48, 32, 24}) {
        if (fixed + (size_t)N_ * c * 8 + 512 <= ws_size) { cap = c; break; }
    }
    int2* es = (int2*)alloc((size_t)N_ * cap * 8);

    hipMemsetAsync(degw, 0, (size_t)N_ * 4, stream);
    hipMemsetAsync(cnt, 0, (size_t)N_ * 4, stream);
    hipMemsetAsync(ovfcnt, 0, 4, stream);

    // hist+scatter (3125) + xcvt (12500) + wprep (64) = 15689 blocks
    fused_prep_kernel<<<15689, 256, 0, stream>>>(src, dst, w, degw, cnt,
                                                 es, cap, ovfcnt, ovf,
                                                 x, xb, Wxz0, Wxz1, Wxh0, Wxh1, swz);

    // 12500 blocks x 4 nodes = 50000
    gather_node_kernel<<<N_ / 4, 256, 0, stream>>>(
        cnt, es, cap, degw, ovfcnt, ovf, xb, swz,
        bxz, bhz, bxh, bhh, Wlin, blin, out);
}

// Round 3
// 407.548 us; speedup vs baseline: 1.0682x; 1.0011x over previous
//
#include <hip/hip_runtime.h>

#define T_ 8
#define N_ 50000
#define E_ 800000
#define C_ 64
#define OVF_CAP 131072

typedef __attribute__((ext_vector_type(8))) short bf16x8;
typedef __attribute__((ext_vector_type(4))) float f32x4;

__device__ inline short f2bf(float f) {
    union { float f; unsigned int u; } v; v.f = f;
    unsigned int u = v.u + 0x7FFFu + ((v.u >> 16) & 1u);  // RNE
    return (short)(u >> 16);
}
__device__ inline float bf2f_lo(unsigned int u) {
    union { unsigned int u; float f; } v; v.u = u << 16;
    return v.f;
}
__device__ inline float bf2f_hi(unsigned int u) {
    union { unsigned int u; float f; } v; v.u = u & 0xffff0000u;
    return v.f;
}

// ---------------------------------------------------------------------------
// 0) weighted out-degree histogram — must complete before nw can be computed
__global__ __launch_bounds__(256) void hist_kernel(const int* __restrict__ src,
                                                   const float* __restrict__ w,
                                                   float* __restrict__ degw) {
    int e = blockIdx.x * 256 + threadIdx.x;  // 3125*256 == E_ exactly
    atomicAdd(&degw[src[e]], w[e]);
}

// ---------------------------------------------------------------------------
// 1) fused: bucket-scatter with INLINE nw (blocks [0,3125)) + xcvt
//    ([3125,15625)) + wprep (rest). degw is complete (hist ran first), so the
//    scatter stores fully-normalized {src, nw} — the gather's hot loop never
//    touches degw/rsqrt. Overflow (deg > cap; impossible here) -> global list.
__global__ __launch_bounds__(256) void fused_prep_kernel(
        const int* __restrict__ src, const int* __restrict__ dst,
        const float* __restrict__ w, const float* __restrict__ degw,
        int* __restrict__ cnt,
        int2* __restrict__ es, int cap,
        int* __restrict__ ovfcnt, int4* __restrict__ ovf,
        const float* __restrict__ x, unsigned short* __restrict__ xb,
        const float* __restrict__ Wz0, const float* __restrict__ Wz1,
        const float* __restrict__ Wh0, const float* __restrict__ Wh1,
        short* __restrict__ swz) {
    if (blockIdx.x < 3125) {
        int e = blockIdx.x * 256 + threadIdx.x;  // 3125*256 == E_ exactly
        int s = src[e], d = dst[e];
        float ds = degw[s], dd = degw[d];
        float is = ds > 0.f ? rsqrtf(fmaxf(ds, 1e-12f)) : 0.f;
        float idv = dd > 0.f ? rsqrtf(fmaxf(dd, 1e-12f)) : 0.f;
        float nwv = -w[e] * is * idv;
        int pos = atomicAdd(&cnt[d], 1);
        if (pos < cap) {
            es[d * cap + pos] = make_int2(s, __float_as_int(nwv));
        } else {
            int op = atomicAdd(ovfcnt, 1);
            if (op < OVF_CAP) ovf[op] = make_int4(d, s, __float_as_int(nwv), 0);
        }
    } else if (blockIdx.x < 15625) {
        // id -> (n, t, c8): write addr (shorts) = n*512 + t*64 + c8*8 = id*8
        int id = (blockIdx.x - 3125) * 256 + threadIdx.x;
        int c8 = id & 7;
        int t = (id >> 3) & 7;
        int n = id >> 6;
        const float* xr = x + ((long long)t * N_ + n) * C_ + c8 * 8;
        float4 a = *(const float4*)(xr);
        float4 b = *(const float4*)(xr + 4);
        bf16x8 o;
        o[0] = f2bf(a.x); o[1] = f2bf(a.y); o[2] = f2bf(a.z); o[3] = f2bf(a.w);
        o[4] = f2bf(b.x); o[5] = f2bf(b.y); o[6] = f2bf(b.z); o[7] = f2bf(b.w);
        *(bf16x8*)(xb + (long long)id * 8) = o;
    } else {
        int idx = (blockIdx.x - 15625) * 256 + threadIdx.x;  // < 16384
        int j = idx & 7;
        int lane = (idx >> 3) & 63;
        int kb = (idx >> 9) & 1;
        int c = (idx >> 10) & 3;
        int mat = idx >> 12;
        const float* W = (mat == 0) ? Wz0 : (mat == 1) ? Wz1 : (mat == 2) ? Wh0 : Wh1;
        int k = kb * 32 + (lane >> 4) * 8 + j;
        int n = c * 16 + (lane & 15);
        swz[idx] = f2bf(W[k * 64 + n]);
    }
}

// accumulate one weighted bf16x8 row-slice into acc[8]
#define ACC8(W, V)                                                       \
    acc[0] += (W) * bf2f_lo((V).x); acc[1] += (W) * bf2f_hi((V).x);      \
    acc[2] += (W) * bf2f_lo((V).y); acc[3] += (W) * bf2f_hi((V).y);      \
    acc[4] += (W) * bf2f_lo((V).z); acc[5] += (W) * bf2f_hi((V).z);      \
    acc[6] += (W) * bf2f_lo((V).w); acc[7] += (W) * bf2f_hi((V).w);

// 2) FUSED gather + node. Block = 4 nodes. Phase 1: each wave gathers one
//    node's tx1 rows (all 8 t) from its bucket — the bucket load is ungated
//    (uniform lane<cap), so it issues in parallel with the cnt load; edges
//    arrive pre-normalized {src, nw}; 4 edges in flight (R1's measured-best
//    depth). Phase 2: waves switch to MFMA roles (wave = M-tile x {az,ah}).
//    Phase 3: az crosses to the ah-wave via LDS, epilogue + Wlin reduce.
__global__ __launch_bounds__(256) void gather_node_kernel(
        const int* __restrict__ cnt, const int2* __restrict__ es, int cap,
        const int* __restrict__ ovfcnt, const int4* __restrict__ ovf,
        const unsigned short* __restrict__ xb, const short* __restrict__ swz,
        const float* __restrict__ bxz, const float* __restrict__ bhz,
        const float* __restrict__ bxh, const float* __restrict__ bhh,
        const float* __restrict__ Wlin, const float* __restrict__ blin,
        float* __restrict__ out) {
    __shared__ unsigned short ltx[32 * 72];  // 32 rows x 64 ch bf16, +8 pad
    __shared__ float laz[2][16][65];         // az exchange, +1 pad

    int lane = threadIdx.x & 63;
    int wid = threadIdx.x >> 6;
    int base = blockIdx.x * 4;

    // ---- phase 1: gather node d = base + wid (lane = t*8 + oct) ----
    {
        int d = base + wid;
        int t = lane >> 3;
        int oct = lane & 7;
        // issue both loads immediately; gate is uniform (no cnt dependency)
        int2 pk = (lane < cap) ? es[d * cap + lane] : make_int2(0, 0);
        int m = cnt[d];
        int mb = m < cap ? m : cap;

        float acc[8] = {0.f, 0.f, 0.f, 0.f, 0.f, 0.f, 0.f, 0.f};
        const unsigned short* xbase = xb + lane * 8;  // node record = 512 shorts
        int k = 0;
        for (; k + 3 < mb; k += 4) {
            int s0 = __shfl(pk.x, k);
            int s1 = __shfl(pk.x, k + 1);
            int s2 = __shfl(pk.x, k + 2);
            int s3 = __shfl(pk.x, k + 3);
            uint4 v0 = *(const uint4*)(xbase + (long long)s0 * 512);
            uint4 v1 = *(const uint4*)(xbase + (long long)s1 * 512);
            uint4 v2 = *(const uint4*)(xbase + (long long)s2 * 512);
            uint4 v3 = *(const uint4*)(xbase + (long long)s3 * 512);
            float w0 = __int_as_float(__shfl(pk.y, k));
            float w1 = __int_as_float(__shfl(pk.y, k + 1));
            float w2 = __int_as_float(__shfl(pk.y, k + 2));
            float w3 = __int_as_float(__shfl(pk.y, k + 3));
            ACC8(w0, v0);
            ACC8(w1, v1);
            ACC8(w2, v2);
            ACC8(w3, v3);
        }
        for (; k < mb; ++k) {
            int s0 = __shfl(pk.x, k);
            float w0 = __int_as_float(__shfl(pk.y, k));
            uint4 v0 = *(const uint4*)(xbase + (long long)s0 * 512);
            ACC8(w0, v0);
        }
        if (m > cap) {  // overflow path: never taken for this input
            int oc = *ovfcnt;
            if (oc > OVF_CAP) oc = OVF_CAP;
            for (int i = 0; i < oc; ++i) {
                int4 o = ovf[i];  // uniform addr -> broadcast
                if (o.x == d) {
                    float w0 = __int_as_float(o.z);
                    uint4 v0 = *(const uint4*)(xbase + (long long)o.y * 512);
                    ACC8(w0, v0);
                }
            }
        }
        uint4 ob;
        ob.x = (unsigned int)(unsigned short)f2bf(acc[0]) |
               ((unsigned int)(unsigned short)f2bf(acc[1]) << 16);
        ob.y = (unsigned int)(unsigned short)f2bf(acc[2]) |
               ((unsigned int)(unsigned short)f2bf(acc[3]) << 16);
        ob.z = (unsigned int)(unsigned short)f2bf(acc[4]) |
               ((unsigned int)(unsigned short)f2bf(acc[5]) << 16);
        ob.w = (unsigned int)(unsigned short)f2bf(acc[6]) |
               ((unsigned int)(unsigned short)f2bf(acc[7]) << 16);
        int r = wid * 8 + t;  // block-row: r>>3 = node, r&7 = t
        *(uint4*)(ltx + r * 72 + oct * 8) = ob;
    }
    __syncthreads();

    // ---- phase 2: MFMA. wave -> (M-tile mt, gate g: 0=az, 1=ah) ----
    int mt = wid >> 1;
    int g = wid & 1;
    int c16 = lane & 15;
    int kq = lane >> 4;
    int r_blk = mt * 16 + c16;
    // node-major row index = node*8 + t = base*8 + r_blk -> contiguous 2 KB/wave
    const unsigned short* xr = xb + (long long)(base * 8 + r_blk) * C_ + kq * 8;
    bf16x8 ax0 = *(const bf16x8*)(xr);
    bf16x8 ax1 = *(const bf16x8*)(xr + 32);
    bf16x8 at0 = *(const bf16x8*)(ltx + r_blk * 72 + kq * 8);
    bf16x8 at1 = *(const bf16x8*)(ltx + r_blk * 72 + 32 + kq * 8);

    const float* bA = g ? bxh : bxz;
    const float* bB = g ? bhh : bhz;
    const short* wA = swz + (2 * g) * 4096 + lane * 8;      // x-weight frags
    const short* wB = swz + (2 * g + 1) * 4096 + lane * 8;  // tx1-weight frags

    f32x4 a4[4];
#pragma unroll
    for (int c = 0; c < 4; ++c) {
        int col = c * 16 + c16;
        float bv = bA[col] + bB[col];
        a4[c] = (f32x4){bv, bv, bv, bv};
    }
#pragma unroll
    for (int c = 0; c < 4; ++c) {
        bf16x8 bA0 = *(const bf16x8*)(wA + (c * 2 + 0) * 512);
        bf16x8 bA1 = *(const bf16x8*)(wA + (c * 2 + 1) * 512);
        bf16x8 bB0 = *(const bf16x8*)(wB + (c * 2 + 0) * 512);
        bf16x8 bB1 = *(const bf16x8*)(wB + (c * 2 + 1) * 512);
        a4[c] = __builtin_amdgcn_mfma_f32_16x16x32_bf16(ax0, bA0, a4[c], 0, 0, 0);
        a4[c] = __builtin_amdgcn_mfma_f32_16x16x32_bf16(ax1, bA1, a4[c], 0, 0, 0);
        a4[c] = __builtin_amdgcn_mfma_f32_16x16x32_bf16(at0, bB0, a4[c], 0, 0, 0);
        a4[c] = __builtin_amdgcn_mfma_f32_16x16x32_bf16(at1, bB1, a4[c], 0, 0, 0);
    }

    // ---- phase 3: az -> LDS; ah-wave computes epilogue ----
    if (g == 0) {
#pragma unroll
        for (int c = 0; c < 4; ++c)
#pragma unroll
            for (int r = 0; r < 4; ++r)
                laz[mt][kq * 4 + r][c * 16 + c16] = a4[c][r];
    }
    __syncthreads();
    if (g == 1) {
        float part[4] = {0.f, 0.f, 0.f, 0.f};
#pragma unroll
        for (int c = 0; c < 4; ++c) {
            int col = c * 16 + c16;
            float wl = Wlin[col];
#pragma unroll
            for (int r = 0; r < 4; ++r) {
                float a = laz[mt][kq * 4 + r][col];
                float b = a4[c][r];
                float z = 1.f / (1.f + __expf(-a));
                float aa = fabsf(b);
                float e = __expf(-2.f * aa);
                float ht = copysignf((1.f - e) / (1.f + e), b);
                float h = fmaxf((1.f - z) * ht, 0.f);
                part[r] += h * wl;
            }
        }
#pragma unroll
        for (int m = 1; m <= 8; m <<= 1) {
#pragma unroll
            for (int r = 0; r < 4; ++r) part[r] += __shfl_xor(part[r], m);
        }
        if (c16 == 0) {
            float bl = blin[0];
#pragma unroll
            for (int r = 0; r < 4; ++r) {
                int rb = mt * 16 + kq * 4 + r;
                out[(long long)(rb & 7) * N_ + base + (rb >> 3)] = part[r] + bl;
            }
        }
    }
}

extern "C" void kernel_launch(void* const* d_in, const int* in_sizes, int n_in,
                              void* d_out, int out_size, void* d_ws, size_t ws_size,
                              hipStream_t stream) {
    const float* x    = (const float*)d_in[0];
    const int*   ei   = (const int*)d_in[1];
    const float* w    = (const float*)d_in[2];
    const float* Wxz0 = (const float*)d_in[3];
    const float* Wxz1 = (const float*)d_in[4];
    const float* bxz  = (const float*)d_in[5];
    const float* bhz  = (const float*)d_in[8];
    const float* Wxh0 = (const float*)d_in[15];
    const float* Wxh1 = (const float*)d_in[16];
    const float* bxh  = (const float*)d_in[17];
    const float* bhh  = (const float*)d_in[20];
    const float* Wlin = (const float*)d_in[21];
    const float* blin = (const float*)d_in[22];
    float* out = (float*)d_out;

    const int* src = ei;
    const int* dst = ei + E_;

    // workspace layout (512-aligned blocks):
    char* ws = (char*)d_ws;
    size_t off = 0;
    auto alloc = [&](size_t bytes) {
        char* p = ws + off;
        off = (off + bytes + 511) & ~(size_t)511;
        return p;
    };
    short* swz         = (short*)alloc(4 * 4096 * sizeof(short));           // 32 KB
    float* degw        = (float*)alloc((size_t)N_ * 4);
    int*   cnt         = (int*)alloc((size_t)N_ * 4);
    int*   ovfcnt      = (int*)alloc(512);
    int4*  ovf         = (int4*)alloc((size_t)OVF_CAP * 16);                // 2 MB
    unsigned short* xb = (unsigned short*)alloc((size_t)T_ * N_ * C_ * 2);  // 51.2 MB
    size_t fixed = off;

    // pick the largest bucket capacity that fits the workspace
    int cap = 16;
    for (int c : {64, 48, 32, 24}) {
        if (fixed + (size_t)N_ * c * 8 + 512 <= ws_size) { cap = c; break; }
    }
    int2* es = (int2*)alloc((size_t)N_ * cap * 8);

    hipMemsetAsync(degw, 0, (size_t)N_ * 4, stream);
    hipMemsetAsync(cnt, 0, (size_t)N_ * 4, stream);
    hipMemsetAsync(ovfcnt, 0, 4, stream);

    // 0) degw histogram (must finish before nw can be computed)
    hist_kernel<<<3125, 256, 0, stream>>>(src, w, degw);

    // 1) scatter-with-nw (3125) + xcvt (12500) + wprep (64) = 15689 blocks
    fused_prep_kernel<<<15689, 256, 0, stream>>>(src, dst, w, degw, cnt,
                                                 es, cap, ovfcnt, ovf,
                                                 x, xb, Wxz0, Wxz1, Wxh0, Wxh1, swz);

    // 2) 12500 blocks x 4 nodes = 50000
    gather_node_kernel<<<N_ / 4, 256, 0, stream>>>(
        cnt, es, cap, ovfcnt, ovf, xb, swz,
        bxz, bhz, bxh, bhh, Wlin, blin, out);
}

// Round 4
// 397.741 us; speedup vs baseline: 1.0946x; 1.0247x over previous
//
#include <hip/hip_runtime.h>

#define T_ 8
#define N_ 50000
#define E_ 800000
#define C_ 64
#define OVF_CAP 131072
#define PAD 16  // one counter per 64 B line: kills same-sector atomic RAW chains

typedef __attribute__((ext_vector_type(8))) short bf16x8;
typedef __attribute__((ext_vector_type(4))) float f32x4;

__device__ inline short f2bf(float f) {
    union { float f; unsigned int u; } v; v.f = f;
    unsigned int u = v.u + 0x7FFFu + ((v.u >> 16) & 1u);  // RNE
    return (short)(u >> 16);
}
__device__ inline float bf2f_lo(unsigned int u) {
    union { unsigned int u; float f; } v; v.u = u << 16;
    return v.f;
}
__device__ inline float bf2f_hi(unsigned int u) {
    union { unsigned int u; float f; } v; v.u = u & 0xffff0000u;
    return v.f;
}

// xcvt helper: one 256-thread block converts 256 (n,t,c8) slices, ids given
__device__ inline void xcvt_step(int id, const float* __restrict__ x,
                                 unsigned short* __restrict__ xb) {
    int c8 = id & 7;
    int t = (id >> 3) & 7;
    int n = id >> 6;
    const float* xr = x + ((long long)t * N_ + n) * C_ + c8 * 8;
    float4 a = *(const float4*)(xr);
    float4 b = *(const float4*)(xr + 4);
    bf16x8 o;
    o[0] = f2bf(a.x); o[1] = f2bf(a.y); o[2] = f2bf(a.z); o[3] = f2bf(a.w);
    o[4] = f2bf(b.x); o[5] = f2bf(b.y); o[6] = f2bf(b.z); o[7] = f2bf(b.w);
    *(bf16x8*)(xb + (long long)id * 8) = o;  // node-major [n][t][c]
}

// ---------------------------------------------------------------------------
// A) degw histogram (padded counters) OVERLAPPED with xcvt first half.
//    blocks [0,3125): hist; [3125, 9375): xcvt ids [0, 1.6M)
__global__ __launch_bounds__(256) void prep_a_kernel(
        const int* __restrict__ src, const float* __restrict__ w,
        float* __restrict__ degw,
        const float* __restrict__ x, unsigned short* __restrict__ xb) {
    if (blockIdx.x < 3125) {
        int e = blockIdx.x * 256 + threadIdx.x;  // 3125*256 == E_ exactly
        atomicAdd(&degw[(long long)src[e] * PAD], w[e]);
    } else {
        int id = (blockIdx.x - 3125) * 256 + threadIdx.x;
        xcvt_step(id, x, xb);
    }
}

// ---------------------------------------------------------------------------
// B) bucket-scatter with inline nw (padded cnt) OVERLAPPED with xcvt second
//    half + wprep. blocks [0,3125): scatter; [3125,9375): xcvt ids
//    [1.6M, 3.2M); [9375, 9439): wprep.
__global__ __launch_bounds__(256) void prep_b_kernel(
        const int* __restrict__ src, const int* __restrict__ dst,
        const float* __restrict__ w, const float* __restrict__ degw,
        int* __restrict__ cnt,
        int2* __restrict__ es, int cap,
        int* __restrict__ ovfcnt, int4* __restrict__ ovf,
        const float* __restrict__ x, unsigned short* __restrict__ xb,
        const float* __restrict__ Wz0, const float* __restrict__ Wz1,
        const float* __restrict__ Wh0, const float* __restrict__ Wh1,
        short* __restrict__ swz) {
    if (blockIdx.x < 3125) {
        int e = blockIdx.x * 256 + threadIdx.x;
        int s = src[e], d = dst[e];
        float ds = degw[(long long)s * PAD], dd = degw[(long long)d * PAD];
        float is = ds > 0.f ? rsqrtf(fmaxf(ds, 1e-12f)) : 0.f;
        float idv = dd > 0.f ? rsqrtf(fmaxf(dd, 1e-12f)) : 0.f;
        float nwv = -w[e] * is * idv;
        int pos = atomicAdd(&cnt[(long long)d * PAD], 1);
        if (pos < cap) {
            es[d * cap + pos] = make_int2(s, __float_as_int(nwv));
        } else {
            int op = atomicAdd(ovfcnt, 1);
            if (op < OVF_CAP) ovf[op] = make_int4(d, s, __float_as_int(nwv), 0);
        }
    } else if (blockIdx.x < 9375) {
        int id = 1600000 + (blockIdx.x - 3125) * 256 + threadIdx.x;
        xcvt_step(id, x, xb);
    } else {
        int idx = (blockIdx.x - 9375) * 256 + threadIdx.x;  // < 16384
        int j = idx & 7;
        int lane = (idx >> 3) & 63;
        int kb = (idx >> 9) & 1;
        int c = (idx >> 10) & 3;
        int mat = idx >> 12;
        const float* W = (mat == 0) ? Wz0 : (mat == 1) ? Wz1 : (mat == 2) ? Wh0 : Wh1;
        int k = kb * 32 + (lane >> 4) * 8 + j;
        int n = c * 16 + (lane & 15);
        swz[idx] = f2bf(W[k * 64 + n]);
    }
}

// accumulate one weighted bf16x8 row-slice into acc[8]
#define ACC8(W, V)                                                       \
    acc[0] += (W) * bf2f_lo((V).x); acc[1] += (W) * bf2f_hi((V).x);      \
    acc[2] += (W) * bf2f_lo((V).y); acc[3] += (W) * bf2f_hi((V).y);      \
    acc[4] += (W) * bf2f_lo((V).z); acc[5] += (W) * bf2f_hi((V).z);      \
    acc[6] += (W) * bf2f_lo((V).w); acc[7] += (W) * bf2f_hi((V).w);

// 2) FUSED gather + node (unchanged from R3's verified-best structure).
__global__ __launch_bounds__(256) void gather_node_kernel(
        const int* __restrict__ cnt, const int2* __restrict__ es, int cap,
        const int* __restrict__ ovfcnt, const int4* __restrict__ ovf,
        const unsigned short* __restrict__ xb, const short* __restrict__ swz,
        const float* __restrict__ bxz, const float* __restrict__ bhz,
        const float* __restrict__ bxh, const float* __restrict__ bhh,
        const float* __restrict__ Wlin, const float* __restrict__ blin,
        float* __restrict__ out) {
    __shared__ unsigned short ltx[32 * 72];  // 32 rows x 64 ch bf16, +8 pad
    __shared__ float laz[2][16][65];         // az exchange, +1 pad

    int lane = threadIdx.x & 63;
    int wid = threadIdx.x >> 6;
    int base = blockIdx.x * 4;

    // ---- phase 1: gather node d = base + wid (lane = t*8 + oct) ----
    {
        int d = base + wid;
        int t = lane >> 3;
        int oct = lane & 7;
        // issue both loads immediately; gate is uniform (no cnt dependency)
        int2 pk = (lane < cap) ? es[d * cap + lane] : make_int2(0, 0);
        int m = cnt[(long long)d * PAD];
        int mb = m < cap ? m : cap;

        float acc[8] = {0.f, 0.f, 0.f, 0.f, 0.f, 0.f, 0.f, 0.f};
        const unsigned short* xbase = xb + lane * 8;  // node record = 512 shorts
        int k = 0;
        for (; k + 3 < mb; k += 4) {
            int s0 = __shfl(pk.x, k);
            int s1 = __shfl(pk.x, k + 1);
            int s2 = __shfl(pk.x, k + 2);
            int s3 = __shfl(pk.x, k + 3);
            uint4 v0 = *(const uint4*)(xbase + (long long)s0 * 512);
            uint4 v1 = *(const uint4*)(xbase + (long long)s1 * 512);
            uint4 v2 = *(const uint4*)(xbase + (long long)s2 * 512);
            uint4 v3 = *(const uint4*)(xbase + (long long)s3 * 512);
            float w0 = __int_as_float(__shfl(pk.y, k));
            float w1 = __int_as_float(__shfl(pk.y, k + 1));
            float w2 = __int_as_float(__shfl(pk.y, k + 2));
            float w3 = __int_as_float(__shfl(pk.y, k + 3));
            ACC8(w0, v0);
            ACC8(w1, v1);
            ACC8(w2, v2);
            ACC8(w3, v3);
        }
        for (; k < mb; ++k) {
            int s0 = __shfl(pk.x, k);
            float w0 = __int_as_float(__shfl(pk.y, k));
            uint4 v0 = *(const uint4*)(xbase + (long long)s0 * 512);
            ACC8(w0, v0);
        }
        if (m > cap) {  // overflow path: never taken for this input
            int oc = *ovfcnt;
            if (oc > OVF_CAP) oc = OVF_CAP;
            for (int i = 0; i < oc; ++i) {
                int4 o = ovf[i];  // uniform addr -> broadcast
                if (o.x == d) {
                    float w0 = __int_as_float(o.z);
                    uint4 v0 = *(const uint4*)(xbase + (long long)o.y * 512);
                    ACC8(w0, v0);
                }
            }
        }
        uint4 ob;
        ob.x = (unsigned int)(unsigned short)f2bf(acc[0]) |
               ((unsigned int)(unsigned short)f2bf(acc[1]) << 16);
        ob.y = (unsigned int)(unsigned short)f2bf(acc[2]) |
               ((unsigned int)(unsigned short)f2bf(acc[3]) << 16);
        ob.z = (unsigned int)(unsigned short)f2bf(acc[4]) |
               ((unsigned int)(unsigned short)f2bf(acc[5]) << 16);
        ob.w = (unsigned int)(unsigned short)f2bf(acc[6]) |
               ((unsigned int)(unsigned short)f2bf(acc[7]) << 16);
        int r = wid * 8 + t;  // block-row: r>>3 = node, r&7 = t
        *(uint4*)(ltx + r * 72 + oct * 8) = ob;
    }
    __syncthreads();

    // ---- phase 2: MFMA. wave -> (M-tile mt, gate g: 0=az, 1=ah) ----
    int mt = wid >> 1;
    int g = wid & 1;
    int c16 = lane & 15;
    int kq = lane >> 4;
    int r_blk = mt * 16 + c16;
    // node-major row index = node*8 + t = base*8 + r_blk -> contiguous 2 KB/wave
    const unsigned short* xr = xb + (long long)(base * 8 + r_blk) * C_ + kq * 8;
    bf16x8 ax0 = *(const bf16x8*)(xr);
    bf16x8 ax1 = *(const bf16x8*)(xr + 32);
    bf16x8 at0 = *(const bf16x8*)(ltx + r_blk * 72 + kq * 8);
    bf16x8 at1 = *(const bf16x8*)(ltx + r_blk * 72 + 32 + kq * 8);

    const float* bA = g ? bxh : bxz;
    const float* bB = g ? bhh : bhz;
    const short* wA = swz + (2 * g) * 4096 + lane * 8;      // x-weight frags
    const short* wB = swz + (2 * g + 1) * 4096 + lane * 8;  // tx1-weight frags

    f32x4 a4[4];
#pragma unroll
    for (int c = 0; c < 4; ++c) {
        int col = c * 16 + c16;
        float bv = bA[col] + bB[col];
        a4[c] = (f32x4){bv, bv, bv, bv};
    }
#pragma unroll
    for (int c = 0; c < 4; ++c) {
        bf16x8 bA0 = *(const bf16x8*)(wA + (c * 2 + 0) * 512);
        bf16x8 bA1 = *(const bf16x8*)(wA + (c * 2 + 1) * 512);
        bf16x8 bB0 = *(const bf16x8*)(wB + (c * 2 + 0) * 512);
        bf16x8 bB1 = *(const bf16x8*)(wB + (c * 2 + 1) * 512);
        a4[c] = __builtin_amdgcn_mfma_f32_16x16x32_bf16(ax0, bA0, a4[c], 0, 0, 0);
        a4[c] = __builtin_amdgcn_mfma_f32_16x16x32_bf16(ax1, bA1, a4[c], 0, 0, 0);
        a4[c] = __builtin_amdgcn_mfma_f32_16x16x32_bf16(at0, bB0, a4[c], 0, 0, 0);
        a4[c] = __builtin_amdgcn_mfma_f32_16x16x32_bf16(at1, bB1, a4[c], 0, 0, 0);
    }

    // ---- phase 3: az -> LDS; ah-wave computes epilogue ----
    if (g == 0) {
#pragma unroll
        for (int c = 0; c < 4; ++c)
#pragma unroll
            for (int r = 0; r < 4; ++r)
                laz[mt][kq * 4 + r][c * 16 + c16] = a4[c][r];
    }
    __syncthreads();
    if (g == 1) {
        float part[4] = {0.f, 0.f, 0.f, 0.f};
#pragma unroll
        for (int c = 0; c < 4; ++c) {
            int col = c * 16 + c16;
            float wl = Wlin[col];
#pragma unroll
            for (int r = 0; r < 4; ++r) {
                float a = laz[mt][kq * 4 + r][col];
                float b = a4[c][r];
                float z = 1.f / (1.f + __expf(-a));
                float aa = fabsf(b);
                float e = __expf(-2.f * aa);
                float ht = copysignf((1.f - e) / (1.f + e), b);
                float h = fmaxf((1.f - z) * ht, 0.f);
                part[r] += h * wl;
            }
        }
#pragma unroll
        for (int m = 1; m <= 8; m <<= 1) {
#pragma unroll
            for (int r = 0; r < 4; ++r) part[r] += __shfl_xor(part[r], m);
        }
        if (c16 == 0) {
            float bl = blin[0];
#pragma unroll
            for (int r = 0; r < 4; ++r) {
                int rb = mt * 16 + kq * 4 + r;
                out[(long long)(rb & 7) * N_ + base + (rb >> 3)] = part[r] + bl;
            }
        }
    }
}

extern "C" void kernel_launch(void* const* d_in, const int* in_sizes, int n_in,
                              void* d_out, int out_size, void* d_ws, size_t ws_size,
                              hipStream_t stream) {
    const float* x    = (const float*)d_in[0];
    const int*   ei   = (const int*)d_in[1];
    const float* w    = (const float*)d_in[2];
    const float* Wxz0 = (const float*)d_in[3];
    const float* Wxz1 = (const float*)d_in[4];
    const float* bxz  = (const float*)d_in[5];
    const float* bhz  = (const float*)d_in[8];
    const float* Wxh0 = (const float*)d_in[15];
    const float* Wxh1 = (const float*)d_in[16];
    const float* bxh  = (const float*)d_in[17];
    const float* bhh  = (const float*)d_in[20];
    const float* Wlin = (const float*)d_in[21];
    const float* blin = (const float*)d_in[22];
    float* out = (float*)d_out;

    const int* src = ei;
    const int* dst = ei + E_;

    // workspace layout (512-aligned blocks):
    char* ws = (char*)d_ws;
    size_t off = 0;
    auto alloc = [&](size_t bytes) {
        char* p = ws + off;
        off = (off + bytes + 511) & ~(size_t)511;
        return p;
    };
    short* swz         = (short*)alloc(4 * 4096 * sizeof(short));            // 32 KB
    float* degw        = (float*)alloc((size_t)N_ * PAD * 4);                // 3.2 MB padded
    int*   cnt         = (int*)alloc((size_t)N_ * PAD * 4);                  // 3.2 MB padded
    int*   ovfcnt      = (int*)alloc(512);
    int4*  ovf         = (int4*)alloc((size_t)OVF_CAP * 16);                 // 2 MB
    unsigned short* xb = (unsigned short*)alloc((size_t)T_ * N_ * C_ * 2);   // 51.2 MB
    size_t fixed = off;

    // pick the largest bucket capacity that fits the workspace
    int cap = 16;
    for (int c : {64, 48, 32, 24}) {
        if (fixed + (size_t)N_ * c * 8 + 512 <= ws_size) { cap = c; break; }
    }
    int2* es = (int2*)alloc((size_t)N_ * cap * 8);

    hipMemsetAsync(degw, 0, (size_t)N_ * PAD * 4, stream);
    hipMemsetAsync(cnt, 0, (size_t)N_ * PAD * 4, stream);
    hipMemsetAsync(ovfcnt, 0, 4, stream);

    // A) degw hist (3125) + xcvt half 1 (6250) = 9375 blocks
    prep_a_kernel<<<9375, 256, 0, stream>>>(src, w, degw, x, xb);

    // B) scatter-with-nw (3125) + xcvt half 2 (6250) + wprep (64) = 9439 blocks
    prep_b_kernel<<<9439, 256, 0, stream>>>(src, dst, w, degw, cnt,
                                            es, cap, ovfcnt, ovf,
                                            x, xb, Wxz0, Wxz1, Wxh0, Wxh1, swz);

    // 2) 12500 blocks x 4 nodes = 50000
    gather_node_kernel<<<N_ / 4, 256, 0, stream>>>(
        cnt, es, cap, ovfcnt, ovf, xb, swz,
        bxz, bhz, bxh, bhh, Wlin, blin, out);
}

// Round 5
// 368.081 us; speedup vs baseline: 1.1828x; 1.0806x over previous
//
#include <hip/hip_runtime.h>

#define T_ 8
#define N_ 50000
#define E_ 800000
#define C_ 64
#define OVF_CAP 131072
#define NB 196     // node buckets (256 nodes each, 196*256 = 50176 >= N)
#define NBLK 256   // edge blocks for the sort (256*3125 = 800000 exactly)
#define EPB 3125   // edges per sort block
#define SCN (2 * NB * NBLK)  // 100352 = 49 * 2048 exactly
#define SCAN_TILES 49

typedef __attribute__((ext_vector_type(8))) short bf16x8;
typedef __attribute__((ext_vector_type(4))) float f32x4;

__device__ inline short f2bf(float f) {
    union { float f; unsigned int u; } v; v.f = f;
    unsigned int u = v.u + 0x7FFFu + ((v.u >> 16) & 1u);  // RNE
    return (short)(u >> 16);
}
__device__ inline float bf2f_lo(unsigned int u) {
    union { unsigned int u; float f; } v; v.u = u << 16;
    return v.f;
}
__device__ inline float bf2f_hi(unsigned int u) {
    union { unsigned int u; float f; } v; v.u = u & 0xffff0000u;
    return v.f;
}

// xcvt helper: convert one (n,t,c8) slice to node-major bf16 xb
__device__ inline void xcvt_step(int id, const float* __restrict__ x,
                                 unsigned short* __restrict__ xb) {
    int c8 = id & 7;
    int t = (id >> 3) & 7;
    int n = id >> 6;
    const float* xr = x + ((long long)t * N_ + n) * C_ + c8 * 8;
    float4 a = *(const float4*)(xr);
    float4 b = *(const float4*)(xr + 4);
    bf16x8 o;
    o[0] = f2bf(a.x); o[1] = f2bf(a.y); o[2] = f2bf(a.z); o[3] = f2bf(a.w);
    o[4] = f2bf(b.x); o[5] = f2bf(b.y); o[6] = f2bf(b.z); o[7] = f2bf(b.w);
    *(bf16x8*)(xb + (long long)id * 8) = o;  // node-major [n][t][c]
}

// ---------------------------------------------------------------------------
// K1: bucket histograms (LDS atomics only) + xcvt + wprep.
//   blocks [0,NBLK): hist of src>>8 and dst>>8 -> counts[row][blk],
//   row = key*NB + bucket; [NBLK, NBLK+12500): xcvt; rest: wprep.
__global__ __launch_bounds__(256) void prep_kernel(
        const int* __restrict__ src, const int* __restrict__ dst,
        int* __restrict__ counts,
        const float* __restrict__ x, unsigned short* __restrict__ xb,
        const float* __restrict__ Wz0, const float* __restrict__ Wz1,
        const float* __restrict__ Wh0, const float* __restrict__ Wh1,
        short* __restrict__ swz) {
    if (blockIdx.x < NBLK) {
        __shared__ int h[2 * NB];
        int t = threadIdx.x;
        for (int i = t; i < 2 * NB; i += 256) h[i] = 0;
        __syncthreads();
        int e0 = blockIdx.x * EPB;
        for (int j = t; j < EPB; j += 256) {
            int e = e0 + j;
            atomicAdd(&h[src[e] >> 8], 1);
            atomicAdd(&h[NB + (dst[e] >> 8)], 1);
        }
        __syncthreads();
        for (int i = t; i < 2 * NB; i += 256)
            counts[i * NBLK + blockIdx.x] = h[i];
    } else if (blockIdx.x < NBLK + 12500) {
        int id = (blockIdx.x - NBLK) * 256 + threadIdx.x;
        xcvt_step(id, x, xb);
    } else {
        int idx = (blockIdx.x - NBLK - 12500) * 256 + threadIdx.x;  // < 16384
        int j = idx & 7;
        int lane = (idx >> 3) & 63;
        int kb = (idx >> 9) & 1;
        int c = (idx >> 10) & 3;
        int mat = idx >> 12;
        const float* W = (mat == 0) ? Wz0 : (mat == 1) ? Wz1 : (mat == 2) ? Wh0 : Wh1;
        int k = kb * 32 + (lane >> 4) * 8 + j;
        int n = c * 16 + (lane & 15);
        swz[idx] = f2bf(W[k * 64 + n]);
    }
}

// K2: scan pass A over the 100352 counts (49 tiles x 2048, exact).
//   In-place exclusive scan within tile + tile totals.
__global__ __launch_bounds__(1024) void scan_a_kernel(int* __restrict__ cnts,
                                                      int* __restrict__ tsum) {
    __shared__ int wsum[16];
    int tid = threadIdx.x, lane = tid & 63, wid = tid >> 6;
    int i0 = blockIdx.x * 2048 + tid * 2;
    int v0 = cnts[i0], v1 = cnts[i0 + 1];
    int orig = v0 + v1;
    int v = orig;
#pragma unroll
    for (int off = 1; off < 64; off <<= 1) {
        int u = __shfl_up(v, off);
        if (lane >= off) v += u;
    }
    if (lane == 63) wsum[wid] = v;
    __syncthreads();
    if (wid == 0) {
        int s = (lane < 16) ? wsum[lane] : 0;
#pragma unroll
        for (int off = 1; off < 16; off <<= 1) {
            int u = __shfl_up(s, off);
            if (lane >= off) s += u;
        }
        if (lane < 16) wsum[lane] = s;
    }
    __syncthreads();
    int wpre = wid ? wsum[wid - 1] : 0;
    int ex = wpre + v - orig;  // exclusive prefix of this thread's pair
    cnts[i0] = ex;
    cnts[i0 + 1] = ex + v0;
    if (tid == 0) tsum[blockIdx.x] = wsum[15];
}

// K3: pass B — every block redundantly scans the 49 tile totals, adds offset.
__global__ __launch_bounds__(1024) void scan_b_kernel(const int* __restrict__ tsum,
                                                      int* __restrict__ cnts) {
    __shared__ int soff[SCAN_TILES];
    int tid = threadIdx.x, lane = tid & 63, wid = tid >> 6;
    if (wid == 0) {
        int own = (lane < SCAN_TILES) ? tsum[lane] : 0;
        int s = own;
#pragma unroll
        for (int off = 1; off < 64; off <<= 1) {
            int u = __shfl_up(s, off);
            if (lane >= off) s += u;
        }
        if (lane < SCAN_TILES) soff[lane] = s - own;  // exclusive
    }
    __syncthreads();
    int off = soff[blockIdx.x];
    int i0 = blockIdx.x * 2048 + tid;
    cnts[i0] += off;
    cnts[i0 + 1024] += off;
}

// K4: deterministic scatter (LDS-ranked, zero global atomics).
//   rec[0, E): src-keyed records {src, w};
//   rec[E, 2E): dst-keyed records {src | dstlow<<16, w}.
__global__ __launch_bounds__(256) void scatter_kernel(
        const int* __restrict__ src, const int* __restrict__ dst,
        const float* __restrict__ w, const int* __restrict__ scn,
        int2* __restrict__ rec) {
    __shared__ int offs[2 * NB];
    int t = threadIdx.x;
    for (int i = t; i < 2 * NB; i += 256)
        offs[i] = scn[i * NBLK + blockIdx.x];
    __syncthreads();
    int e0 = blockIdx.x * EPB;
    for (int j = t; j < EPB; j += 256) {
        int e = e0 + j;
        int s = src[e], d = dst[e];
        float wv = w[e];
        int r0 = atomicAdd(&offs[s >> 8], 1);           // LDS atomic
        rec[r0] = make_int2(s, __float_as_int(wv));
        int r1 = atomicAdd(&offs[NB + (d >> 8)], 1);    // LDS atomic
        rec[r1] = make_int2(s | ((d & 255) << 16), __float_as_int(wv));
    }
}

// K5: degw = segmented sum of src-keyed records per bucket (no global atomics)
__global__ __launch_bounds__(256) void degw_kernel(
        const int2* __restrict__ rec, const int* __restrict__ scn,
        float* __restrict__ degw) {
    __shared__ float acc[256];
    int t = threadIdx.x, b = blockIdx.x;
    acc[t] = 0.f;
    __syncthreads();
    int s0 = scn[b * NBLK];
    int s1 = (b == NB - 1) ? E_ : scn[(b + 1) * NBLK];
    for (int j = s0 + t; j < s1; j += 256) {
        int2 r = rec[j];
        atomicAdd(&acc[r.x & 255], __int_as_float(r.y));  // LDS fp32 atomic
    }
    __syncthreads();
    int node = b * 256 + t;
    if (node < N_) degw[node] = acc[t];
}

// K6: build es buckets + cnt from dst-keyed records, nw inline (degw is done).
__global__ __launch_bounds__(256) void esbuild_kernel(
        const int2* __restrict__ rec, const int* __restrict__ scn,
        const float* __restrict__ degw, int* __restrict__ cnt,
        int2* __restrict__ es, int cap,
        int* __restrict__ ovfcnt, int4* __restrict__ ovf) {
    __shared__ int cl[256];
    __shared__ float di[256];
    int t = threadIdx.x, b = blockIdx.x;
    cl[t] = 0;
    int node = b * 256 + t;
    float dd = (node < N_) ? degw[node] : 0.f;
    di[t] = dd > 0.f ? rsqrtf(fmaxf(dd, 1e-12f)) : 0.f;
    __syncthreads();
    int s0 = scn[(NB + b) * NBLK];
    int s1 = (b == NB - 1) ? 2 * E_ : scn[(NB + b + 1) * NBLK];
    for (int j = s0 + t; j < s1; j += 256) {
        int2 r = rec[j];
        int s = r.x & 0xffff;          // src < 50000 fits 16 bits
        int dl = (r.x >> 16) & 255;
        float ds = degw[s];            // L2-resident random read
        float is = ds > 0.f ? rsqrtf(fmaxf(ds, 1e-12f)) : 0.f;
        float nwv = -__int_as_float(r.y) * is * di[dl];
        int rank = atomicAdd(&cl[dl], 1);  // LDS atomic
        int d = b * 256 + dl;
        if (rank < cap) {
            es[d * cap + rank] = make_int2(s, __float_as_int(nwv));
        } else {
            int op = atomicAdd(ovfcnt, 1);
            if (op < OVF_CAP) ovf[op] = make_int4(d, s, __float_as_int(nwv), 0);
        }
    }
    __syncthreads();
    if (node < N_) cnt[node] = cl[t];
}

// accumulate one weighted bf16x8 row-slice into acc[8]
#define ACC8(W, V)                                                       \
    acc[0] += (W) * bf2f_lo((V).x); acc[1] += (W) * bf2f_hi((V).x);      \
    acc[2] += (W) * bf2f_lo((V).y); acc[3] += (W) * bf2f_hi((V).y);      \
    acc[4] += (W) * bf2f_lo((V).z); acc[5] += (W) * bf2f_hi((V).z);      \
    acc[6] += (W) * bf2f_lo((V).w); acc[7] += (W) * bf2f_hi((V).w);

// K7: FUSED gather + node (R3/R4's verified structure; cnt now compact).
__global__ __launch_bounds__(256) void gather_node_kernel(
        const int* __restrict__ cnt, const int2* __restrict__ es, int cap,
        const int* __restrict__ ovfcnt, const int4* __restrict__ ovf,
        const unsigned short* __restrict__ xb, const short* __restrict__ swz,
        const float* __restrict__ bxz, const float* __restrict__ bhz,
        const float* __restrict__ bxh, const float* __restrict__ bhh,
        const float* __restrict__ Wlin, const float* __restrict__ blin,
        float* __restrict__ out) {
    __shared__ unsigned short ltx[32 * 72];  // 32 rows x 64 ch bf16, +8 pad
    __shared__ float laz[2][16][65];         // az exchange, +1 pad

    int lane = threadIdx.x & 63;
    int wid = threadIdx.x >> 6;
    int base = blockIdx.x * 4;

    // ---- phase 1: gather node d = base + wid (lane = t*8 + oct) ----
    {
        int d = base + wid;
        int t = lane >> 3;
        int oct = lane & 7;
        // issue both loads immediately; gate is uniform (no cnt dependency)
        int2 pk = (lane < cap) ? es[d * cap + lane] : make_int2(0, 0);
        int m = cnt[d];
        int mb = m < cap ? m : cap;

        float acc[8] = {0.f, 0.f, 0.f, 0.f, 0.f, 0.f, 0.f, 0.f};
        const unsigned short* xbase = xb + lane * 8;  // node record = 512 shorts
        int k = 0;
        for (; k + 3 < mb; k += 4) {
            int s0 = __shfl(pk.x, k);
            int s1 = __shfl(pk.x, k + 1);
            int s2 = __shfl(pk.x, k + 2);
            int s3 = __shfl(pk.x, k + 3);
            uint4 v0 = *(const uint4*)(xbase + (long long)s0 * 512);
            uint4 v1 = *(const uint4*)(xbase + (long long)s1 * 512);
            uint4 v2 = *(const uint4*)(xbase + (long long)s2 * 512);
            uint4 v3 = *(const uint4*)(xbase + (long long)s3 * 512);
            float w0 = __int_as_float(__shfl(pk.y, k));
            float w1 = __int_as_float(__shfl(pk.y, k + 1));
            float w2 = __int_as_float(__shfl(pk.y, k + 2));
            float w3 = __int_as_float(__shfl(pk.y, k + 3));
            ACC8(w0, v0);
            ACC8(w1, v1);
            ACC8(w2, v2);
            ACC8(w3, v3);
        }
        for (; k < mb; ++k) {
            int s0 = __shfl(pk.x, k);
            float w0 = __int_as_float(__shfl(pk.y, k));
            uint4 v0 = *(const uint4*)(xbase + (long long)s0 * 512);
            ACC8(w0, v0);
        }
        if (m > cap) {  // overflow path: never taken for this input
            int oc = *ovfcnt;
            if (oc > OVF_CAP) oc = OVF_CAP;
            for (int i = 0; i < oc; ++i) {
                int4 o = ovf[i];  // uniform addr -> broadcast
                if (o.x == d) {
                    float w0 = __int_as_float(o.z);
                    uint4 v0 = *(const uint4*)(xbase + (long long)o.y * 512);
                    ACC8(w0, v0);
                }
            }
        }
        uint4 ob;
        ob.x = (unsigned int)(unsigned short)f2bf(acc[0]) |
               ((unsigned int)(unsigned short)f2bf(acc[1]) << 16);
        ob.y = (unsigned int)(unsigned short)f2bf(acc[2]) |
               ((unsigned int)(unsigned short)f2bf(acc[3]) << 16);
        ob.z = (unsigned int)(unsigned short)f2bf(acc[4]) |
               ((unsigned int)(unsigned short)f2bf(acc[5]) << 16);
        ob.w = (unsigned int)(unsigned short)f2bf(acc[6]) |
               ((unsigned int)(unsigned short)f2bf(acc[7]) << 16);
        int r = wid * 8 + t;  // block-row: r>>3 = node, r&7 = t
        *(uint4*)(ltx + r * 72 + oct * 8) = ob;
    }
    __syncthreads();

    // ---- phase 2: MFMA. wave -> (M-tile mt, gate g: 0=az, 1=ah) ----
    int mt = wid >> 1;
    int g = wid & 1;
    int c16 = lane & 15;
    int kq = lane >> 4;
    int r_blk = mt * 16 + c16;
    // node-major row index = node*8 + t = base*8 + r_blk -> contiguous 2 KB/wave
    const unsigned short* xr = xb + (long long)(base * 8 + r_blk) * C_ + kq * 8;
    bf16x8 ax0 = *(const bf16x8*)(xr);
    bf16x8 ax1 = *(const bf16x8*)(xr + 32);
    bf16x8 at0 = *(const bf16x8*)(ltx + r_blk * 72 + kq * 8);
    bf16x8 at1 = *(const bf16x8*)(ltx + r_blk * 72 + 32 + kq * 8);

    const float* bA = g ? bxh : bxz;
    const float* bB = g ? bhh : bhz;
    const short* wA = swz + (2 * g) * 4096 + lane * 8;      // x-weight frags
    const short* wB = swz + (2 * g + 1) * 4096 + lane * 8;  // tx1-weight frags

    f32x4 a4[4];
#pragma unroll
    for (int c = 0; c < 4; ++c) {
        int col = c * 16 + c16;
        float bv = bA[col] + bB[col];
        a4[c] = (f32x4){bv, bv, bv, bv};
    }
#pragma unroll
    for (int c = 0; c < 4; ++c) {
        bf16x8 bA0 = *(const bf16x8*)(wA + (c * 2 + 0) * 512);
        bf16x8 bA1 = *(const bf16x8*)(wA + (c * 2 + 1) * 512);
        bf16x8 bB0 = *(const bf16x8*)(wB + (c * 2 + 0) * 512);
        bf16x8 bB1 = *(const bf16x8*)(wB + (c * 2 + 1) * 512);
        a4[c] = __builtin_amdgcn_mfma_f32_16x16x32_bf16(ax0, bA0, a4[c], 0, 0, 0);
        a4[c] = __builtin_amdgcn_mfma_f32_16x16x32_bf16(ax1, bA1, a4[c], 0, 0, 0);
        a4[c] = __builtin_amdgcn_mfma_f32_16x16x32_bf16(at0, bB0, a4[c], 0, 0, 0);
        a4[c] = __builtin_amdgcn_mfma_f32_16x16x32_bf16(at1, bB1, a4[c], 0, 0, 0);
    }

    // ---- phase 3: az -> LDS; ah-wave computes epilogue ----
    if (g == 0) {
#pragma unroll
        for (int c = 0; c < 4; ++c)
#pragma unroll
            for (int r = 0; r < 4; ++r)
                laz[mt][kq * 4 + r][c * 16 + c16] = a4[c][r];
    }
    __syncthreads();
    if (g == 1) {
        float part[4] = {0.f, 0.f, 0.f, 0.f};
#pragma unroll
        for (int c = 0; c < 4; ++c) {
            int col = c * 16 + c16;
            float wl = Wlin[col];
#pragma unroll
            for (int r = 0; r < 4; ++r) {
                float a = laz[mt][kq * 4 + r][col];
                float b = a4[c][r];
                float z = 1.f / (1.f + __expf(-a));
                float aa = fabsf(b);
                float e = __expf(-2.f * aa);
                float ht = copysignf((1.f - e) / (1.f + e), b);
                float h = fmaxf((1.f - z) * ht, 0.f);
                part[r] += h * wl;
            }
        }
#pragma unroll
        for (int m = 1; m <= 8; m <<= 1) {
#pragma unroll
            for (int r = 0; r < 4; ++r) part[r] += __shfl_xor(part[r], m);
        }
        if (c16 == 0) {
            float bl = blin[0];
#pragma unroll
            for (int r = 0; r < 4; ++r) {
                int rb = mt * 16 + kq * 4 + r;
                out[(long long)(rb & 7) * N_ + base + (rb >> 3)] = part[r] + bl;
            }
        }
    }
}

extern "C" void kernel_launch(void* const* d_in, const int* in_sizes, int n_in,
                              void* d_out, int out_size, void* d_ws, size_t ws_size,
                              hipStream_t stream) {
    const float* x    = (const float*)d_in[0];
    const int*   ei   = (const int*)d_in[1];
    const float* w    = (const float*)d_in[2];
    const float* Wxz0 = (const float*)d_in[3];
    const float* Wxz1 = (const float*)d_in[4];
    const float* bxz  = (const float*)d_in[5];
    const float* bhz  = (const float*)d_in[8];
    const float* Wxh0 = (const float*)d_in[15];
    const float* Wxh1 = (const float*)d_in[16];
    const float* bxh  = (const float*)d_in[17];
    const float* bhh  = (const float*)d_in[20];
    const float* Wlin = (const float*)d_in[21];
    const float* blin = (const float*)d_in[22];
    float* out = (float*)d_out;

    const int* src = ei;
    const int* dst = ei + E_;

    // workspace layout (512-aligned blocks):
    char* ws = (char*)d_ws;
    size_t off = 0;
    auto alloc = [&](size_t bytes) {
        char* p = ws + off;
        off = (off + bytes + 511) & ~(size_t)511;
        return p;
    };
    short* swz         = (short*)alloc(4 * 4096 * sizeof(short));           // 32 KB
    float* degw        = (float*)alloc((size_t)N_ * 4);                     // 200 KB
    int*   cnt         = (int*)alloc((size_t)N_ * 4);                       // 200 KB
    int*   ovfcnt      = (int*)alloc(512);
    int4*  ovf         = (int4*)alloc((size_t)OVF_CAP * 16);                // 2 MB
    int*   counts      = (int*)alloc((size_t)SCN * 4);                      // 401 KB
    int*   tsum        = (int*)alloc((size_t)SCAN_TILES * 4);
    int2*  rec         = (int2*)alloc((size_t)2 * E_ * 8);                  // 12.8 MB
    unsigned short* xb = (unsigned short*)alloc((size_t)T_ * N_ * C_ * 2);  // 51.2 MB
    size_t fixed = off;

    // pick the largest bucket capacity that fits the workspace
    int cap = 16;
    for (int c : {64, 48, 32, 24}) {
        if (fixed + (size_t)N_ * c * 8 + 512 <= ws_size) { cap = c; break; }
    }
    int2* es = (int2*)alloc((size_t)N_ * cap * 8);

    hipMemsetAsync(ovfcnt, 0, 4, stream);

    // K1: hist (256) + xcvt (12500) + wprep (64) = 12820 blocks
    prep_kernel<<<NBLK + 12500 + 64, 256, 0, stream>>>(
        src, dst, counts, x, xb, Wxz0, Wxz1, Wxh0, Wxh1, swz);

    // K2/K3: exclusive scan of the 100352-entry count matrix
    scan_a_kernel<<<SCAN_TILES, 1024, 0, stream>>>(counts, tsum);
    scan_b_kernel<<<SCAN_TILES, 1024, 0, stream>>>(tsum, counts);

    // K4: deterministic two-key scatter into rec (no global atomics)
    scatter_kernel<<<NBLK, 256, 0, stream>>>(src, dst, w, counts, rec);

    // K5: degw segmented reduce (src-keyed half)
    degw_kernel<<<NB, 256, 0, stream>>>(rec, counts, degw);

    // K6: es buckets + cnt + inline nw (dst-keyed half)
    esbuild_kernel<<<NB, 256, 0, stream>>>(rec, counts, degw, cnt,
                                           es, cap, ovfcnt, ovf);

    // K7: 12500 blocks x 4 nodes = 50000
    gather_node_kernel<<<N_ / 4, 256, 0, stream>>>(
        cnt, es, cap, ovfcnt, ovf, xb, swz,
        bxz, bhz, bxh, bhh, Wlin, blin, out);
}